// Round 5
// baseline (2917.820 us; speedup 1.0000x reference)
//
#include <hip/hip_runtime.h>
#include <hip/hip_bf16.h>
#include <math.h>

#define H 64
#define F 18

typedef _Float16 half2_t __attribute__((ext_vector_type(2)));

// ---------------------------------------------------------------- embed ----
// writes x as f16 [N][64]
__global__ __launch_bounds__(256) void embed_kernel(
    const float* __restrict__ nf, const float* __restrict__ W,
    const float* __restrict__ b, half2_t* __restrict__ xh, int N)
{
    int n = blockIdx.x * 256 + threadIdx.x;
    if (n >= N) return;
    float acc[H];
#pragma unroll
    for (int j = 0; j < H; ++j) acc[j] = b[j];
    const float* f = nf + (long)n * F;
#pragma unroll
    for (int i = 0; i < F; ++i) {
        float c = f[i];
        const float* w = W + i * H;
#pragma unroll
        for (int j = 0; j < H; ++j) acc[j] += c * w[j];
    }
    union { uint4 v[8]; half2_t h[32]; } O;
#pragma unroll
    for (int j2 = 0; j2 < 32; ++j2) {
        half2_t p;
        p.x = (_Float16)fmaxf(acc[2 * j2], 0.f);
        p.y = (_Float16)fmaxf(acc[2 * j2 + 1], 0.f);
        O.h[j2] = p;
    }
    uint4* xo = (uint4*)(xh + (size_t)n * 32);
#pragma unroll
    for (int i = 0; i < 8; ++i) xo[i] = O.v[i];
}

// ------------------------------------------------------- weight prepack ---
// Wp[l][k2][j] = half2(W[2k2][j], W[2k2+1][j]); j<64 -> msgW1, j>=64 -> attW1
__global__ __launch_bounds__(256) void packw_kernel(
    const float* __restrict__ mW1, const float* __restrict__ aW1,
    half2_t* __restrict__ Wp)
{
    int idx = blockIdx.x * 256 + threadIdx.x;
    if (idx >= 2 * 64 * 96) return;
    int l = idx / (64 * 96);
    int r = idx % (64 * 96);
    int k2 = r / 96, j = r % 96;
    float a, bb;
    if (j < 64) {
        const float* W = mW1 + (size_t)l * 128 * 64;
        a = W[(2 * k2) * 64 + j];
        bb = W[(2 * k2 + 1) * 64 + j];
    } else {
        const float* W = aW1 + (size_t)l * 128 * 32;
        a = W[(2 * k2) * 32 + (j - 64)];
        bb = W[(2 * k2 + 1) * 32 + (j - 64)];
    }
    half2_t h;
    h.x = (_Float16)a;
    h.y = (_Float16)bb;
    Wp[idx] = h;
}

// ----------------------------------------------- counting sort by col -----
__global__ __launch_bounds__(256) void hist_kernel(
    const int* __restrict__ col, int* __restrict__ deg, int E)
{
    int e = blockIdx.x * 256 + threadIdx.x;
    if (e < E) atomicAdd(deg + col[e], 1);
}

__global__ __launch_bounds__(256) void scan1_kernel(
    const int* __restrict__ deg, int* __restrict__ part,
    int* __restrict__ bsum, int N)
{
    __shared__ int lds[256];
    int t = threadIdx.x;
    int base = blockIdx.x * 1024 + t * 4;
    int v[4];
#pragma unroll
    for (int s = 0; s < 4; ++s) v[s] = (base + s < N) ? deg[base + s] : 0;
    int sum = v[0] + v[1] + v[2] + v[3];
    lds[t] = sum;
    __syncthreads();
    for (int off = 1; off < 256; off <<= 1) {
        int xv = (t >= off) ? lds[t - off] : 0;
        __syncthreads();
        lds[t] += xv;
        __syncthreads();
    }
    int excl = lds[t] - sum;
    if (t == 255) bsum[blockIdx.x] = lds[255];
    int p = excl;
#pragma unroll
    for (int s = 0; s < 4; ++s) {
        if (base + s < N) part[base + s] = p;
        p += v[s];
    }
}

__global__ __launch_bounds__(256) void scan2_kernel(int* __restrict__ bsum, int nb)
{
    __shared__ int lds[256];
    int t = threadIdx.x;
    int v = (t < nb) ? bsum[t] : 0;
    lds[t] = v;
    __syncthreads();
    for (int off = 1; off < 256; off <<= 1) {
        int xv = (t >= off) ? lds[t - off] : 0;
        __syncthreads();
        lds[t] += xv;
        __syncthreads();
    }
    if (t < nb) bsum[t] = lds[t] - v;
}

__global__ __launch_bounds__(256) void scan3_kernel(
    int* __restrict__ part, const int* __restrict__ bsum,
    int* __restrict__ cursor, int N)
{
    int i = blockIdx.x * 256 + threadIdx.x;
    if (i >= N) return;
    int s = part[i] + bsum[i >> 10];
    part[i] = s;
    cursor[i] = s;
}

__global__ __launch_bounds__(256) void scatter_kernel(
    const int* __restrict__ row, const int* __restrict__ col,
    const float* __restrict__ ew, int* __restrict__ cursor,
    int* __restrict__ rowS, int* __restrict__ colS,
    float* __restrict__ ewS, int E)
{
    int e = blockIdx.x * 256 + threadIdx.x;
    if (e >= E) return;
    int c = col[e];
    int p = atomicAdd(cursor + c, 1);
    rowS[p] = row[e];
    colS[p] = c;
    ewS[p] = ew[e];
}

// ----------------------------------------------------------------- edge ----
// lane = sorted-edge; x in f16, weights prepacked half2 -> v_dot2_f32_f16
// (2 MACs/instr, fp32 accumulate). colS sorted -> x[colS] L1-resident.
__global__ __launch_bounds__(256) void edge_kernel(
    const half2_t* __restrict__ xh,
    const int* __restrict__ rowS, const int* __restrict__ colS,
    const float* __restrict__ ewS,
    const half2_t* __restrict__ Wp,   // [64][96]
    const float* __restrict__ b1, const float* __restrict__ ab1,
    const float* __restrict__ aW2, const float* __restrict__ ab2,
    __hip_bfloat16* __restrict__ hfw, float* __restrict__ fwbuf,
    int e0, int e1)
{
    int e = e0 + blockIdx.x * 256 + threadIdx.x;
    if (e >= e1) return;

    union { uint4 v[8]; half2_t h[32]; } R, C;
    const uint4* pr = (const uint4*)(xh + (size_t)rowS[e] * 32);
    const uint4* pc = (const uint4*)(xh + (size_t)colS[e] * 32);
#pragma unroll
    for (int i = 0; i < 8; ++i) R.v[i] = pr[i];
#pragma unroll
    for (int i = 0; i < 8; ++i) C.v[i] = pc[i];

    // ---- attention head ----
    float fw;
    {
        float acca[32];
#pragma unroll
        for (int j = 0; j < 32; ++j) acca[j] = 0.f;
        for (int k2 = 0; k2 < 32; ++k2) {
            half2_t c2 = R.h[k2];
            const half2_t* w = Wp + k2 * 96 + 64;
#pragma unroll
            for (int j = 0; j < 32; ++j)
                acca[j] = __builtin_amdgcn_fdot2(c2, w[j], acca[j], false);
        }
        for (int k2 = 0; k2 < 32; ++k2) {
            half2_t c2 = C.h[k2];
            const half2_t* w = Wp + (32 + k2) * 96 + 64;
#pragma unroll
            for (int j = 0; j < 32; ++j)
                acca[j] = __builtin_amdgcn_fdot2(c2, w[j], acca[j], false);
        }
        float za = ab2[0];
#pragma unroll
        for (int k = 0; k < 32; ++k)
            za += fmaxf(acca[k] + ab1[k], 0.f) * aW2[k];
        fw = ewS[e] / (1.f + __expf(-za));
    }

    // ---- message layer 1 ----
    float accm[H];
#pragma unroll
    for (int j = 0; j < H; ++j) accm[j] = 0.f;
    for (int k2 = 0; k2 < 32; ++k2) {
        half2_t c2 = R.h[k2];
        const half2_t* w = Wp + k2 * 96;
#pragma unroll
        for (int j = 0; j < H; ++j)
            accm[j] = __builtin_amdgcn_fdot2(c2, w[j], accm[j], false);
    }
    for (int k2 = 0; k2 < 32; ++k2) {
        half2_t c2 = C.h[k2];
        const half2_t* w = Wp + (32 + k2) * 96;
#pragma unroll
        for (int j = 0; j < H; ++j)
            accm[j] = __builtin_amdgcn_fdot2(c2, w[j], accm[j], false);
    }

    int le = e - e0;
    uint4* out = (uint4*)(hfw + (size_t)le * H);
#pragma unroll
    for (int g = 0; g < H / 8; ++g) {
        union { unsigned short u[8]; uint4 v; } pk;
#pragma unroll
        for (int s = 0; s < 8; ++s) {
            float val = fmaxf(accm[8 * g + s] + b1[8 * g + s], 0.f) * fw;
            __hip_bfloat16 hb = __float2bfloat16(val);
            pk.u[s] = *reinterpret_cast<unsigned short*>(&hb);
        }
        out[g] = pk.v;
    }
    fwbuf[le] = fw;
}

// --------------------------------------------------------------- gather ----
__global__ __launch_bounds__(256) void gather_kernel(
    const __hip_bfloat16* __restrict__ hfw, const float* __restrict__ fwbuf,
    const int* __restrict__ startp, const int* __restrict__ deg,
    float* __restrict__ agg, float* __restrict__ fwsum,
    int N, int e0, int e1)
{
    int wid = (blockIdx.x * 256 + threadIdx.x) >> 6;
    int lane = threadIdx.x & 63;
    if (wid >= N) return;
    int s = startp[wid];
    int endv = s + deg[wid];
    int lo = s > e0 ? s : e0;
    int hi = endv < e1 ? endv : e1;
    if (lo >= hi) return;
    int d = hi - lo;
    int base = lo - e0;
    float acc = 0.f;
    const __hip_bfloat16* hp = hfw + (size_t)base * H + lane;
    for (int i = 0; i < d; ++i) acc += __bfloat162float(hp[(size_t)i * H]);
    float fwl = 0.f;
    for (int i = lane; i < d; i += 64) fwl += fwbuf[base + i];
#pragma unroll
    for (int off = 32; off > 0; off >>= 1) fwl += __shfl_down(fwl, off);
    agg[(size_t)wid * H + lane] += acc;
    if (lane == 0) fwsum[wid] += fwl;
}

// --------------------------------------------------------------- update ----
__global__ __launch_bounds__(256) void update_kernel(
    half2_t* __restrict__ xh, const float* __restrict__ agg,
    const float* __restrict__ fwsum,
    const float* __restrict__ mW2, const float* __restrict__ mb2,
    const float* __restrict__ W1, const float* __restrict__ b1,
    const float* __restrict__ W2, const float* __restrict__ b2, int N)
{
    int n = blockIdx.x * 256 + threadIdx.x;
    if (n >= N) return;
    float fws = fwsum[n];
    float inv = 1.f / fmaxf(fws, 1e-6f);

    union { uint4 v[8]; half2_t h[32]; } X;
    const uint4* xa = (const uint4*)(xh + (size_t)n * 32);
#pragma unroll
    for (int i = 0; i < 8; ++i) X.v[i] = xa[i];
    float xf[H];
#pragma unroll
    for (int j2 = 0; j2 < 32; ++j2) {
        xf[2 * j2] = (float)X.h[j2].x;
        xf[2 * j2 + 1] = (float)X.h[j2].y;
    }

    float aggv[H];
#pragma unroll
    for (int j = 0; j < H; ++j) aggv[j] = fws * mb2[j];
    const float4* ga = (const float4*)(agg + (size_t)n * H);
    for (int i4 = 0; i4 < H / 4; ++i4) {
        float4 v = ga[i4];
#pragma unroll
        for (int s = 0; s < 4; ++s) {
            float cs = (s == 0) ? v.x : (s == 1) ? v.y : (s == 2) ? v.z : v.w;
            const float* w = mW2 + (i4 * 4 + s) * H;
#pragma unroll
            for (int j = 0; j < H; ++j) aggv[j] += cs * w[j];
        }
    }
#pragma unroll
    for (int j = 0; j < H; ++j) aggv[j] *= inv;

    float accu[H];
#pragma unroll
    for (int j = 0; j < H; ++j) accu[j] = 0.f;
#pragma unroll
    for (int k = 0; k < H; ++k) {
        float cs = xf[k];
        const float* w = W1 + k * H;
#pragma unroll
        for (int j = 0; j < H; ++j) accu[j] += cs * w[j];
    }
#pragma unroll
    for (int k = 0; k < H; ++k) {
        float cs = aggv[k];
        const float* w = W1 + (H + k) * H;
#pragma unroll
        for (int j = 0; j < H; ++j) accu[j] += cs * w[j];
    }

    float h[H];
#pragma unroll
    for (int k = 0; k < H; ++k) h[k] = fmaxf(accu[k] + b1[k], 0.f);
    float acc2[H];
#pragma unroll
    for (int j = 0; j < H; ++j) acc2[j] = b2[j];
#pragma unroll
    for (int k = 0; k < H; ++k) {
        float hk = h[k];
        const float* w = W2 + k * H;
#pragma unroll
        for (int j = 0; j < H; ++j) acc2[j] += hk * w[j];
    }

    union { uint4 v[8]; half2_t h[32]; } O;
#pragma unroll
    for (int j2 = 0; j2 < 32; ++j2) {
        half2_t p;
        p.x = (_Float16)fmaxf(acc2[2 * j2] + xf[2 * j2], 0.f);
        p.y = (_Float16)fmaxf(acc2[2 * j2 + 1] + xf[2 * j2 + 1], 0.f);
        O.h[j2] = p;
    }
    uint4* xo = (uint4*)(xh + (size_t)n * 32);
#pragma unroll
    for (int i = 0; i < 8; ++i) xo[i] = O.v[i];
}

// ----------------------------------------------------------------- head ----
__global__ __launch_bounds__(256) void max_kernel(
    const _Float16* __restrict__ xh16, unsigned int* __restrict__ serp, int N)
{
    int j = threadIdx.x & (H - 1);
    int g = (blockIdx.x * 256 + threadIdx.x) >> 6;
    int stride = (gridDim.x * 256) >> 6;
    float m = 0.f;  // x >= 0 after relu
    for (int n = g; n < N; n += stride)
        m = fmaxf(m, (float)xh16[(size_t)n * H + j]);
    atomicMax(serp + j, __float_as_uint(m));
}

__global__ void head_kernel(const unsigned int* __restrict__ serp,
                            const float* __restrict__ hW,
                            const float* __restrict__ hb,
                            float* __restrict__ out)
{
    int j = threadIdx.x;  // 64 threads = 1 wave
    float v = __uint_as_float(serp[j]) * hW[j];
#pragma unroll
    for (int off = 32; off > 0; off >>= 1) v += __shfl_down(v, off);
    if (j == 0) out[0] = v + hb[0];
}

// --------------------------------------------------------------- launch ----
extern "C" void kernel_launch(void* const* d_in, const int* in_sizes, int n_in,
                              void* d_out, int out_size, void* d_ws, size_t ws_size,
                              hipStream_t stream)
{
    const float* nf  = (const float*)d_in[0];
    const int*   ei  = (const int*)d_in[1];
    const float* ew  = (const float*)d_in[2];
    const float* eW  = (const float*)d_in[3];
    const float* eb  = (const float*)d_in[4];
    const float* mW1 = (const float*)d_in[5];
    const float* mb1 = (const float*)d_in[6];
    const float* mW2 = (const float*)d_in[7];
    const float* mb2 = (const float*)d_in[8];
    const float* aW1 = (const float*)d_in[9];
    const float* ab1 = (const float*)d_in[10];
    const float* aW2 = (const float*)d_in[11];
    const float* ab2 = (const float*)d_in[12];
    const float* uW1 = (const float*)d_in[13];
    const float* ub1 = (const float*)d_in[14];
    const float* uW2 = (const float*)d_in[15];
    const float* ub2 = (const float*)d_in[16];
    const float* hW  = (const float*)d_in[17];
    const float* hb  = (const float*)d_in[18];

    int N = in_sizes[0] / F;
    int E = in_sizes[2];
    const int* row = ei;
    const int* col = ei + E;

    size_t Nr = ((size_t)N + 3) & ~(size_t)3;
    size_t Er = ((size_t)E + 3) & ~(size_t)3;

    // pick smallest chunk count k whose layout fits ws_size
    int k = 16;
    size_t ce = 0;
    const int kcand[5] = {1, 2, 4, 8, 16};
    for (int i = 0; i < 5; ++i) {
        int kk = kcand[i];
        size_t c = (((size_t)E + kk - 1) / kk + 3) & ~(size_t)3;
        size_t elems = Nr * H / 2     // xh (f16)
                     + Nr * H         // agg
                     + Nr             // fwsum
                     + 64             // serp
                     + 3 * Nr         // deg, startp, cursor
                     + 256            // bsum
                     + 12288          // Wp (2*64*96 half2)
                     + 3 * Er         // rowS, colS, ewS
                     + c              // fwbuf
                     + c * H / 2;     // hfw (bf16)
        if (elems * 4 <= ws_size || i == 4) { k = kk; ce = c; break; }
    }
    int chunkE = (int)ce;

    half2_t* xh   = (half2_t*)d_ws;                   // Nr*32 half2
    float* agg    = (float*)d_ws + Nr * H / 2;        // Nr*H
    float* fwsum  = agg + Nr * H;                     // Nr
    unsigned int* serp = (unsigned int*)(fwsum + Nr); // 64
    int*   deg    = (int*)(serp + 64);                // Nr
    int*   startp = deg + Nr;                         // Nr
    int*   cursor = startp + Nr;                      // Nr
    int*   bsum   = cursor + Nr;                      // 256
    half2_t* Wp   = (half2_t*)(bsum + 256);           // 12288
    int*   rowS   = (int*)(Wp + 12288);               // Er
    int*   colS   = rowS + Er;                        // Er
    float* ewS    = (float*)(colS + Er);              // Er
    float* fwbuf  = ewS + Er;                         // ce
    __hip_bfloat16* hfw = (__hip_bfloat16*)(fwbuf + ce);  // ce*H bf16

    int nb_n = (N + 255) / 256;
    int nb_e = (E + 255) / 256;
    int nb_scan = (N + 1023) / 1024;  // <=256 (N<=262144)

    // ---- counting sort by destination (reused by both layers) ----
    hipMemsetAsync(deg, 0, (size_t)N * sizeof(int), stream);
    hist_kernel<<<nb_e, 256, 0, stream>>>(col, deg, E);
    scan1_kernel<<<nb_scan, 256, 0, stream>>>(deg, startp, bsum, N);
    scan2_kernel<<<1, 256, 0, stream>>>(bsum, nb_scan);
    scan3_kernel<<<nb_n, 256, 0, stream>>>(startp, bsum, cursor, N);
    scatter_kernel<<<nb_e, 256, 0, stream>>>(row, col, ew, cursor,
                                             rowS, colS, ewS, E);

    packw_kernel<<<48, 256, 0, stream>>>(mW1, aW1, Wp);
    embed_kernel<<<nb_n, 256, 0, stream>>>(nf, eW, eb, xh, N);

    for (int l = 0; l < 2; ++l) {
        hipMemsetAsync(agg, 0, (Nr * H + Nr) * sizeof(float), stream);
        for (int c = 0; c < k; ++c) {
            int e0 = c * chunkE;
            if (e0 >= E) break;
            int e1 = (e0 + chunkE < E) ? e0 + chunkE : E;
            int nb_c = (e1 - e0 + 255) / 256;
            edge_kernel<<<nb_c, 256, 0, stream>>>(
                xh, rowS, colS, ewS,
                Wp + (size_t)l * 6144,
                mb1 + (size_t)l * H,
                ab1 + (size_t)l * (H / 2),
                aW2 + (size_t)l * (H / 2), ab2 + (size_t)l,
                hfw, fwbuf, e0, e1);
            gather_kernel<<<(N + 3) / 4, 256, 0, stream>>>(
                hfw, fwbuf, startp, deg, agg, fwsum, N, e0, e1);
        }
        update_kernel<<<nb_n, 256, 0, stream>>>(
            xh, agg, fwsum,
            mW2 + (size_t)l * H * H,     mb2 + (size_t)l * H,
            uW1 + (size_t)l * 2 * H * H, ub1 + (size_t)l * H,
            uW2 + (size_t)l * H * H,     ub2 + (size_t)l * H, N);
    }

    hipMemsetAsync(serp, 0, 64 * sizeof(unsigned int), stream);
    max_kernel<<<256, 256, 0, stream>>>((const _Float16*)xh, serp, N);
    head_kernel<<<1, 64, 0, stream>>>(serp, hW, hb, (float*)d_out);
}

// Round 6
// 1587.165 us; speedup vs baseline: 1.8384x; 1.8384x over previous
//
#include <hip/hip_runtime.h>
#include <hip/hip_bf16.h>
#include <math.h>

#define H 64
#define F 18

typedef _Float16 half2_t __attribute__((ext_vector_type(2)));

// ---------------------------------------------------------------- embed ----
// writes x as f16 [N][64]
__global__ __launch_bounds__(256) void embed_kernel(
    const float* __restrict__ nf, const float* __restrict__ W,
    const float* __restrict__ b, half2_t* __restrict__ xh, int N)
{
    int n = blockIdx.x * 256 + threadIdx.x;
    if (n >= N) return;
    float acc[H];
#pragma unroll
    for (int j = 0; j < H; ++j) acc[j] = b[j];
    const float* f = nf + (long)n * F;
#pragma unroll
    for (int i = 0; i < F; ++i) {
        float c = f[i];
        const float* w = W + i * H;
#pragma unroll
        for (int j = 0; j < H; ++j) acc[j] += c * w[j];
    }
    union { uint4 v[8]; half2_t h[32]; } O;
#pragma unroll
    for (int j2 = 0; j2 < 32; ++j2) {
        half2_t p;
        p.x = (_Float16)fmaxf(acc[2 * j2], 0.f);
        p.y = (_Float16)fmaxf(acc[2 * j2 + 1], 0.f);
        O.h[j2] = p;
    }
    uint4* xo = (uint4*)(xh + (size_t)n * 32);
#pragma unroll
    for (int i = 0; i < 8; ++i) xo[i] = O.v[i];
}

// ------------------------------------------------------- weight prepack ---
// Wp[l][k2][j] = half2(W[2k2][j], W[2k2+1][j]); j<64 -> msgW1, j>=64 -> attW1
__global__ __launch_bounds__(256) void packw_kernel(
    const float* __restrict__ mW1, const float* __restrict__ aW1,
    half2_t* __restrict__ Wp)
{
    int idx = blockIdx.x * 256 + threadIdx.x;
    if (idx >= 2 * 64 * 96) return;
    int l = idx / (64 * 96);
    int r = idx % (64 * 96);
    int k2 = r / 96, j = r % 96;
    float a, bb;
    if (j < 64) {
        const float* W = mW1 + (size_t)l * 128 * 64;
        a = W[(2 * k2) * 64 + j];
        bb = W[(2 * k2 + 1) * 64 + j];
    } else {
        const float* W = aW1 + (size_t)l * 128 * 32;
        a = W[(2 * k2) * 32 + (j - 64)];
        bb = W[(2 * k2 + 1) * 32 + (j - 64)];
    }
    half2_t h;
    h.x = (_Float16)a;
    h.y = (_Float16)bb;
    Wp[idx] = h;
}

// ----------------------------------------------- counting sort by col -----
__global__ __launch_bounds__(256) void hist_kernel(
    const int* __restrict__ col, int* __restrict__ deg, int E)
{
    int e = blockIdx.x * 256 + threadIdx.x;
    if (e < E) atomicAdd(deg + col[e], 1);
}

__global__ __launch_bounds__(256) void scan1_kernel(
    const int* __restrict__ deg, int* __restrict__ part,
    int* __restrict__ bsum, int N)
{
    __shared__ int lds[256];
    int t = threadIdx.x;
    int base = blockIdx.x * 1024 + t * 4;
    int v[4];
#pragma unroll
    for (int s = 0; s < 4; ++s) v[s] = (base + s < N) ? deg[base + s] : 0;
    int sum = v[0] + v[1] + v[2] + v[3];
    lds[t] = sum;
    __syncthreads();
    for (int off = 1; off < 256; off <<= 1) {
        int xv = (t >= off) ? lds[t - off] : 0;
        __syncthreads();
        lds[t] += xv;
        __syncthreads();
    }
    int excl = lds[t] - sum;
    if (t == 255) bsum[blockIdx.x] = lds[255];
    int p = excl;
#pragma unroll
    for (int s = 0; s < 4; ++s) {
        if (base + s < N) part[base + s] = p;
        p += v[s];
    }
}

__global__ __launch_bounds__(256) void scan2_kernel(int* __restrict__ bsum, int nb)
{
    __shared__ int lds[256];
    int t = threadIdx.x;
    int v = (t < nb) ? bsum[t] : 0;
    lds[t] = v;
    __syncthreads();
    for (int off = 1; off < 256; off <<= 1) {
        int xv = (t >= off) ? lds[t - off] : 0;
        __syncthreads();
        lds[t] += xv;
        __syncthreads();
    }
    if (t < nb) bsum[t] = lds[t] - v;
}

__global__ __launch_bounds__(256) void scan3_kernel(
    int* __restrict__ part, const int* __restrict__ bsum,
    int* __restrict__ cursor, int N)
{
    int i = blockIdx.x * 256 + threadIdx.x;
    if (i >= N) return;
    int s = part[i] + bsum[i >> 10];
    part[i] = s;
    cursor[i] = s;
}

__global__ __launch_bounds__(256) void scatter_kernel(
    const int* __restrict__ row, const int* __restrict__ col,
    const float* __restrict__ ew, int* __restrict__ cursor,
    int* __restrict__ rowS, int* __restrict__ colS,
    float* __restrict__ ewS, int E)
{
    int e = blockIdx.x * 256 + threadIdx.x;
    if (e >= E) return;
    int c = col[e];
    int p = atomicAdd(cursor + c, 1);
    rowS[p] = row[e];
    colS[p] = c;
    ewS[p] = ew[e];
}

// ----------------------------------------------------------------- edge ----
// lane = sorted-edge; dot2 f16 with REGISTER-PRESSURE DISCIPLINE:
//   - loads stream inside the k-loop (no preloaded row arrays; L1 serves
//     the 3 passes over the same 256B)
//   - att phase: 32 acc; msg phase j-blocked 2x32 acc
// Peak live ~45 VGPR -> no scratch spills (R5 failure mode).
__global__ __launch_bounds__(256) void edge_kernel(
    const uint4* __restrict__ xh4,   // [N][8] uint4 of f16
    const int* __restrict__ rowS, const int* __restrict__ colS,
    const float* __restrict__ ewS,
    const half2_t* __restrict__ Wp,  // [64][96]
    const float* __restrict__ b1, const float* __restrict__ ab1,
    const float* __restrict__ aW2, const float* __restrict__ ab2,
    __hip_bfloat16* __restrict__ hfw, float* __restrict__ fwbuf,
    int e0, int e1)
{
    int e = e0 + blockIdx.x * 256 + threadIdx.x;
    if (e >= e1) return;
    const uint4* pr = xh4 + (size_t)rowS[e] * 8;
    const uint4* pc = xh4 + (size_t)colS[e] * 8;

    // ---- attention head (32 acc) ----
    float fw;
    {
        float acca[32];
#pragma unroll
        for (int j = 0; j < 32; ++j) acca[j] = 0.f;
#pragma unroll
        for (int half = 0; half < 2; ++half) {
            const uint4* src = half ? pc : pr;
            for (int i = 0; i < 8; ++i) {
                union { uint4 v; half2_t h[4]; } U;
                U.v = src[i];
#pragma unroll
                for (int s = 0; s < 4; ++s) {
                    const half2_t* w = Wp + (half * 32 + i * 4 + s) * 96 + 64;
#pragma unroll
                    for (int j = 0; j < 32; ++j)
                        acca[j] = __builtin_amdgcn_fdot2(U.h[s], w[j], acca[j], false);
                }
            }
        }
        float za = ab2[0];
#pragma unroll
        for (int k = 0; k < 32; ++k)
            za += fmaxf(acca[k] + ab1[k], 0.f) * aW2[k];
        fw = ewS[e] / (1.f + __expf(-za));
    }

    // ---- message layer 1, j-blocked 2x32 ----
    int le = e - e0;
    uint4* out = (uint4*)(hfw + (size_t)le * H);
#pragma unroll
    for (int jb = 0; jb < 2; ++jb) {
        float accm[32];
#pragma unroll
        for (int j = 0; j < 32; ++j) accm[j] = 0.f;
#pragma unroll
        for (int half = 0; half < 2; ++half) {
            const uint4* src = half ? pc : pr;
            for (int i = 0; i < 8; ++i) {
                union { uint4 v; half2_t h[4]; } U;
                U.v = src[i];
#pragma unroll
                for (int s = 0; s < 4; ++s) {
                    const half2_t* w = Wp + (half * 32 + i * 4 + s) * 96 + jb * 32;
#pragma unroll
                    for (int j = 0; j < 32; ++j)
                        accm[j] = __builtin_amdgcn_fdot2(U.h[s], w[j], accm[j], false);
                }
            }
        }
#pragma unroll
        for (int g = 0; g < 4; ++g) {
            union { unsigned short u[8]; uint4 v; } pk;
#pragma unroll
            for (int s = 0; s < 8; ++s) {
                int j = 8 * g + s;
                float val = fmaxf(accm[j] + b1[jb * 32 + j], 0.f) * fw;
                __hip_bfloat16 hb = __float2bfloat16(val);
                pk.u[s] = *reinterpret_cast<unsigned short*>(&hb);
            }
            out[jb * 4 + g] = pk.v;
        }
    }
    fwbuf[le] = fw;
}

// --------------------------------------------------------------- gather ----
__global__ __launch_bounds__(256) void gather_kernel(
    const __hip_bfloat16* __restrict__ hfw, const float* __restrict__ fwbuf,
    const int* __restrict__ startp, const int* __restrict__ deg,
    float* __restrict__ agg, float* __restrict__ fwsum,
    int N, int e0, int e1)
{
    int wid = (blockIdx.x * 256 + threadIdx.x) >> 6;
    int lane = threadIdx.x & 63;
    if (wid >= N) return;
    int s = startp[wid];
    int endv = s + deg[wid];
    int lo = s > e0 ? s : e0;
    int hi = endv < e1 ? endv : e1;
    if (lo >= hi) return;
    int d = hi - lo;
    int base = lo - e0;
    float acc = 0.f;
    const __hip_bfloat16* hp = hfw + (size_t)base * H + lane;
    for (int i = 0; i < d; ++i) acc += __bfloat162float(hp[(size_t)i * H]);
    float fwl = 0.f;
    for (int i = lane; i < d; i += 64) fwl += fwbuf[base + i];
#pragma unroll
    for (int off = 32; off > 0; off >>= 1) fwl += __shfl_down(fwl, off);
    agg[(size_t)wid * H + lane] += acc;
    if (lane == 0) fwsum[wid] += fwl;
}

// --------------------------------------------------------------- update ----
__global__ __launch_bounds__(256) void update_kernel(
    half2_t* __restrict__ xh, const float* __restrict__ agg,
    const float* __restrict__ fwsum,
    const float* __restrict__ mW2, const float* __restrict__ mb2,
    const float* __restrict__ W1, const float* __restrict__ b1,
    const float* __restrict__ W2, const float* __restrict__ b2, int N)
{
    int n = blockIdx.x * 256 + threadIdx.x;
    if (n >= N) return;
    float fws = fwsum[n];
    float inv = 1.f / fmaxf(fws, 1e-6f);

    union { uint4 v[8]; half2_t h[32]; } X;
    const uint4* xa = (const uint4*)(xh + (size_t)n * 32);
#pragma unroll
    for (int i = 0; i < 8; ++i) X.v[i] = xa[i];
    float xf[H];
#pragma unroll
    for (int j2 = 0; j2 < 32; ++j2) {
        xf[2 * j2] = (float)X.h[j2].x;
        xf[2 * j2 + 1] = (float)X.h[j2].y;
    }

    float aggv[H];
#pragma unroll
    for (int j = 0; j < H; ++j) aggv[j] = fws * mb2[j];
    const float4* ga = (const float4*)(agg + (size_t)n * H);
    for (int i4 = 0; i4 < H / 4; ++i4) {
        float4 v = ga[i4];
#pragma unroll
        for (int s = 0; s < 4; ++s) {
            float cs = (s == 0) ? v.x : (s == 1) ? v.y : (s == 2) ? v.z : v.w;
            const float* w = mW2 + (i4 * 4 + s) * H;
#pragma unroll
            for (int j = 0; j < H; ++j) aggv[j] += cs * w[j];
        }
    }
#pragma unroll
    for (int j = 0; j < H; ++j) aggv[j] *= inv;

    float accu[H];
#pragma unroll
    for (int j = 0; j < H; ++j) accu[j] = 0.f;
#pragma unroll
    for (int k = 0; k < H; ++k) {
        float cs = xf[k];
        const float* w = W1 + k * H;
#pragma unroll
        for (int j = 0; j < H; ++j) accu[j] += cs * w[j];
    }
#pragma unroll
    for (int k = 0; k < H; ++k) {
        float cs = aggv[k];
        const float* w = W1 + (H + k) * H;
#pragma unroll
        for (int j = 0; j < H; ++j) accu[j] += cs * w[j];
    }

    float h[H];
#pragma unroll
    for (int k = 0; k < H; ++k) h[k] = fmaxf(accu[k] + b1[k], 0.f);
    float acc2[H];
#pragma unroll
    for (int j = 0; j < H; ++j) acc2[j] = b2[j];
#pragma unroll
    for (int k = 0; k < H; ++k) {
        float hk = h[k];
        const float* w = W2 + k * H;
#pragma unroll
        for (int j = 0; j < H; ++j) acc2[j] += hk * w[j];
    }

    union { uint4 v[8]; half2_t h[32]; } O;
#pragma unroll
    for (int j2 = 0; j2 < 32; ++j2) {
        half2_t p;
        p.x = (_Float16)fmaxf(acc2[2 * j2] + xf[2 * j2], 0.f);
        p.y = (_Float16)fmaxf(acc2[2 * j2 + 1] + xf[2 * j2 + 1], 0.f);
        O.h[j2] = p;
    }
    uint4* xo = (uint4*)(xh + (size_t)n * 32);
#pragma unroll
    for (int i = 0; i < 8; ++i) xo[i] = O.v[i];
}

// ----------------------------------------------------------------- head ----
__global__ __launch_bounds__(256) void max_kernel(
    const _Float16* __restrict__ xh16, unsigned int* __restrict__ serp, int N)
{
    int j = threadIdx.x & (H - 1);
    int g = (blockIdx.x * 256 + threadIdx.x) >> 6;
    int stride = (gridDim.x * 256) >> 6;
    float m = 0.f;  // x >= 0 after relu
    for (int n = g; n < N; n += stride)
        m = fmaxf(m, (float)xh16[(size_t)n * H + j]);
    atomicMax(serp + j, __float_as_uint(m));
}

__global__ void head_kernel(const unsigned int* __restrict__ serp,
                            const float* __restrict__ hW,
                            const float* __restrict__ hb,
                            float* __restrict__ out)
{
    int j = threadIdx.x;  // 64 threads = 1 wave
    float v = __uint_as_float(serp[j]) * hW[j];
#pragma unroll
    for (int off = 32; off > 0; off >>= 1) v += __shfl_down(v, off);
    if (j == 0) out[0] = v + hb[0];
}

// --------------------------------------------------------------- launch ----
extern "C" void kernel_launch(void* const* d_in, const int* in_sizes, int n_in,
                              void* d_out, int out_size, void* d_ws, size_t ws_size,
                              hipStream_t stream)
{
    const float* nf  = (const float*)d_in[0];
    const int*   ei  = (const int*)d_in[1];
    const float* ew  = (const float*)d_in[2];
    const float* eW  = (const float*)d_in[3];
    const float* eb  = (const float*)d_in[4];
    const float* mW1 = (const float*)d_in[5];
    const float* mb1 = (const float*)d_in[6];
    const float* mW2 = (const float*)d_in[7];
    const float* mb2 = (const float*)d_in[8];
    const float* aW1 = (const float*)d_in[9];
    const float* ab1 = (const float*)d_in[10];
    const float* aW2 = (const float*)d_in[11];
    const float* ab2 = (const float*)d_in[12];
    const float* uW1 = (const float*)d_in[13];
    const float* ub1 = (const float*)d_in[14];
    const float* uW2 = (const float*)d_in[15];
    const float* ub2 = (const float*)d_in[16];
    const float* hW  = (const float*)d_in[17];
    const float* hb  = (const float*)d_in[18];

    int N = in_sizes[0] / F;
    int E = in_sizes[2];
    const int* row = ei;
    const int* col = ei + E;

    size_t Nr = ((size_t)N + 3) & ~(size_t)3;
    size_t Er = ((size_t)E + 3) & ~(size_t)3;

    // pick smallest chunk count k whose layout fits ws_size
    int k = 16;
    size_t ce = 0;
    const int kcand[5] = {1, 2, 4, 8, 16};
    for (int i = 0; i < 5; ++i) {
        int kk = kcand[i];
        size_t c = (((size_t)E + kk - 1) / kk + 3) & ~(size_t)3;
        size_t elems = Nr * H / 2     // xh (f16)
                     + Nr * H         // agg
                     + Nr             // fwsum
                     + 64             // serp
                     + 3 * Nr         // deg, startp, cursor
                     + 256            // bsum
                     + 12288          // Wp (2*64*96 half2)
                     + 3 * Er         // rowS, colS, ewS
                     + c              // fwbuf
                     + c * H / 2;     // hfw (bf16)
        if (elems * 4 <= ws_size || i == 4) { k = kk; ce = c; break; }
    }
    int chunkE = (int)ce;

    half2_t* xh   = (half2_t*)d_ws;                   // Nr*32 half2
    float* agg    = (float*)d_ws + Nr * H / 2;        // Nr*H
    float* fwsum  = agg + Nr * H;                     // Nr
    unsigned int* serp = (unsigned int*)(fwsum + Nr); // 64
    int*   deg    = (int*)(serp + 64);                // Nr
    int*   startp = deg + Nr;                         // Nr
    int*   cursor = startp + Nr;                      // Nr
    int*   bsum   = cursor + Nr;                      // 256
    half2_t* Wp   = (half2_t*)(bsum + 256);           // 12288
    int*   rowS   = (int*)(Wp + 12288);               // Er
    int*   colS   = rowS + Er;                        // Er
    float* ewS    = (float*)(colS + Er);              // Er
    float* fwbuf  = ewS + Er;                         // ce
    __hip_bfloat16* hfw = (__hip_bfloat16*)(fwbuf + ce);  // ce*H bf16

    int nb_n = (N + 255) / 256;
    int nb_e = (E + 255) / 256;
    int nb_scan = (N + 1023) / 1024;  // <=256 (N<=262144)

    // ---- counting sort by destination (reused by both layers) ----
    hipMemsetAsync(deg, 0, (size_t)N * sizeof(int), stream);
    hist_kernel<<<nb_e, 256, 0, stream>>>(col, deg, E);
    scan1_kernel<<<nb_scan, 256, 0, stream>>>(deg, startp, bsum, N);
    scan2_kernel<<<1, 256, 0, stream>>>(bsum, nb_scan);
    scan3_kernel<<<nb_n, 256, 0, stream>>>(startp, bsum, cursor, N);
    scatter_kernel<<<nb_e, 256, 0, stream>>>(row, col, ew, cursor,
                                             rowS, colS, ewS, E);

    packw_kernel<<<48, 256, 0, stream>>>(mW1, aW1, Wp);
    embed_kernel<<<nb_n, 256, 0, stream>>>(nf, eW, eb, xh, N);

    for (int l = 0; l < 2; ++l) {
        hipMemsetAsync(agg, 0, (Nr * H + Nr) * sizeof(float), stream);
        for (int c = 0; c < k; ++c) {
            int e0 = c * chunkE;
            if (e0 >= E) break;
            int e1 = (e0 + chunkE < E) ? e0 + chunkE : E;
            int nb_c = (e1 - e0 + 255) / 256;
            edge_kernel<<<nb_c, 256, 0, stream>>>(
                (const uint4*)xh, rowS, colS, ewS,
                Wp + (size_t)l * 6144,
                mb1 + (size_t)l * H,
                ab1 + (size_t)l * (H / 2),
                aW2 + (size_t)l * (H / 2), ab2 + (size_t)l,
                hfw, fwbuf, e0, e1);
            gather_kernel<<<(N + 3) / 4, 256, 0, stream>>>(
                hfw, fwbuf, startp, deg, agg, fwsum, N, e0, e1);
        }
        update_kernel<<<nb_n, 256, 0, stream>>>(
            xh, agg, fwsum,
            mW2 + (size_t)l * H * H,     mb2 + (size_t)l * H,
            uW1 + (size_t)l * 2 * H * H, ub1 + (size_t)l * H,
            uW2 + (size_t)l * H * H,     ub2 + (size_t)l * H, N);
    }

    hipMemsetAsync(serp, 0, 64 * sizeof(unsigned int), stream);
    max_kernel<<<256, 256, 0, stream>>>((const _Float16*)xh, serp, N);
    head_kernel<<<1, 64, 0, stream>>>(serp, hW, hb, (float*)d_out);
}

// Round 7
// 1214.978 us; speedup vs baseline: 2.4015x; 1.3063x over previous
//
#include <hip/hip_runtime.h>
#include <hip/hip_bf16.h>
#include <math.h>

#define H 64
#define F 18

typedef _Float16 f16x8 __attribute__((ext_vector_type(8)));
typedef float f32x4 __attribute__((ext_vector_type(4)));

// ---------------------------------------------------------------- embed ----
// writes x as f16 [N][64]
__global__ __launch_bounds__(256) void embed_kernel(
    const float* __restrict__ nf, const float* __restrict__ W,
    const float* __restrict__ b, _Float16* __restrict__ xh, int N)
{
    int n = blockIdx.x * 256 + threadIdx.x;
    if (n >= N) return;
    float acc[H];
#pragma unroll
    for (int j = 0; j < H; ++j) acc[j] = b[j];
    const float* f = nf + (long)n * F;
#pragma unroll
    for (int i = 0; i < F; ++i) {
        float c = f[i];
        const float* w = W + i * H;
#pragma unroll
        for (int j = 0; j < H; ++j) acc[j] += c * w[j];
    }
    union { uint4 v[8]; _Float16 h[64]; } O;
#pragma unroll
    for (int j = 0; j < H; ++j) O.h[j] = (_Float16)fmaxf(acc[j], 0.f);
    uint4* xo = (uint4*)(xh + (size_t)n * H);
#pragma unroll
    for (int i = 0; i < 8; ++i) xo[i] = O.v[i];
}

// ------------------------------------------------- B-fragment prepack -----
// MFMA 16x16x32 B-operand layout: lane holds B[k = kk*32 + (lane>>4)*8 + j]
// [n = ntile*16 + (lane&15)], j=0..7. Frag buffers are lane-ordered so the
// edge kernel loads them as coalesced dwordx4.
// msgB: [layer][ntile(4)*4+kk][lane]   attB: [layer][ntile(2)*4+kk][lane]
__global__ __launch_bounds__(256) void packfrag_kernel(
    const float* __restrict__ mW1, const float* __restrict__ aW1,
    f16x8* __restrict__ msgB, f16x8* __restrict__ attB)
{
    int t = blockIdx.x * 256 + threadIdx.x;  // 0..3071
    if (t >= 3072) return;
    int lane = t & 63;
    int frag = t >> 6;            // 0..47
    int l = frag / 24, f = frag % 24;
    int quad = lane >> 4, l15 = lane & 15;
    f16x8 v;
    if (f < 16) {
        int nt = f >> 2, kk = f & 3;
        const float* W = mW1 + (size_t)l * 128 * 64;
#pragma unroll
        for (int j = 0; j < 8; ++j) {
            int k = kk * 32 + quad * 8 + j;
            v[j] = (_Float16)W[k * 64 + nt * 16 + l15];
        }
        msgB[((size_t)l * 16 + f) * 64 + lane] = v;
    } else {
        int f2 = f - 16;
        int nt = f2 >> 2, kk = f2 & 3;
        const float* W = aW1 + (size_t)l * 128 * 32;
#pragma unroll
        for (int j = 0; j < 8; ++j) {
            int k = kk * 32 + quad * 8 + j;
            v[j] = (_Float16)W[k * 32 + nt * 16 + l15];
        }
        attB[((size_t)l * 8 + f2) * 64 + lane] = v;
    }
}

// ----------------------------------------------- counting sort by col -----
__global__ __launch_bounds__(256) void hist_kernel(
    const int* __restrict__ col, int* __restrict__ deg, int E)
{
    int e = blockIdx.x * 256 + threadIdx.x;
    if (e < E) atomicAdd(deg + col[e], 1);
}

__global__ __launch_bounds__(256) void scan1_kernel(
    const int* __restrict__ deg, int* __restrict__ part,
    int* __restrict__ bsum, int N)
{
    __shared__ int lds[256];
    int t = threadIdx.x;
    int base = blockIdx.x * 1024 + t * 4;
    int v[4];
#pragma unroll
    for (int s = 0; s < 4; ++s) v[s] = (base + s < N) ? deg[base + s] : 0;
    int sum = v[0] + v[1] + v[2] + v[3];
    lds[t] = sum;
    __syncthreads();
    for (int off = 1; off < 256; off <<= 1) {
        int xv = (t >= off) ? lds[t - off] : 0;
        __syncthreads();
        lds[t] += xv;
        __syncthreads();
    }
    int excl = lds[t] - sum;
    if (t == 255) bsum[blockIdx.x] = lds[255];
    int p = excl;
#pragma unroll
    for (int s = 0; s < 4; ++s) {
        if (base + s < N) part[base + s] = p;
        p += v[s];
    }
}

__global__ __launch_bounds__(256) void scan2_kernel(int* __restrict__ bsum, int nb)
{
    __shared__ int lds[256];
    int t = threadIdx.x;
    int v = (t < nb) ? bsum[t] : 0;
    lds[t] = v;
    __syncthreads();
    for (int off = 1; off < 256; off <<= 1) {
        int xv = (t >= off) ? lds[t - off] : 0;
        __syncthreads();
        lds[t] += xv;
        __syncthreads();
    }
    if (t < nb) bsum[t] = lds[t] - v;
}

__global__ __launch_bounds__(256) void scan3_kernel(
    int* __restrict__ part, const int* __restrict__ bsum,
    int* __restrict__ cursor, int N)
{
    int i = blockIdx.x * 256 + threadIdx.x;
    if (i >= N) return;
    int s = part[i] + bsum[i >> 10];
    part[i] = s;
    cursor[i] = s;
}

__global__ __launch_bounds__(256) void scatter_kernel(
    const int* __restrict__ row, const int* __restrict__ col,
    const float* __restrict__ ew, int* __restrict__ cursor,
    int* __restrict__ rowS, int* __restrict__ colS,
    float* __restrict__ ewS, int E)
{
    int e = blockIdx.x * 256 + threadIdx.x;
    if (e >= E) return;
    int c = col[e];
    int p = atomicAdd(cursor + c, 1);
    rowS[p] = row[e];
    colS[p] = c;
    ewS[p] = ew[e];
}

// ----------------------------------------------------------------- edge ----
// MFMA 16x16x32 f16. Wave = 64 edges (4 M-tiles of 16).
//  A-frag: lane holds cat[m=lane&15][k=quad*8+j] -> two 16B loads per x row,
//          no LDS. B-frags preloaded from packed buffers (held in VGPRs).
//  att C/D rows (edge=quad*4+reg) match msg C/D rows, so fw flows in-reg
//  from the 16-lane shfl_xor butterfly into the msg epilogue.
__global__ __launch_bounds__(256) void edge_mfma_kernel(
    const _Float16* __restrict__ xh,
    const int* __restrict__ rowS, const int* __restrict__ colS,
    const float* __restrict__ ewS,
    const f16x8* __restrict__ msgB,  // [16][64] for this layer
    const f16x8* __restrict__ attB,  // [8][64]
    const float* __restrict__ b1, const float* __restrict__ ab1,
    const float* __restrict__ aW2, const float* __restrict__ ab2,
    __hip_bfloat16* __restrict__ hfw, float* __restrict__ fwbuf,
    int e0, int e1)
{
    int wid = (blockIdx.x * 256 + threadIdx.x) >> 6;
    int lane = threadIdx.x & 63;
    int ebase = e0 + wid * 64;
    if (ebase >= e1) return;
    int quad = lane >> 4, l15 = lane & 15;

    // B fragments (held in registers)
    f16x8 mb[4][4], ab[2][4];
#pragma unroll
    for (int nt = 0; nt < 4; ++nt)
#pragma unroll
        for (int kk = 0; kk < 4; ++kk)
            mb[nt][kk] = msgB[(nt * 4 + kk) * 64 + lane];
#pragma unroll
    for (int nt = 0; nt < 2; ++nt)
#pragma unroll
        for (int kk = 0; kk < 4; ++kk)
            ab[nt][kk] = attB[(nt * 4 + kk) * 64 + lane];

    float ab1v0 = ab1[l15], ab1v1 = ab1[16 + l15];
    float aw20 = aW2[l15], aw21 = aW2[16 + l15];
    float ab2v = ab2[0];
    float bm[4];
#pragma unroll
    for (int nt = 0; nt < 4; ++nt) bm[nt] = b1[nt * 16 + l15];

    for (int mt = 0; mt < 4; ++mt) {
        int ea = ebase + mt * 16 + l15;       // A-row edge for this lane
        if (ea >= e1) ea = e1 - 1;
        const f16x8* rowp = (const f16x8*)(xh + (size_t)rowS[ea] * H);
        const f16x8* colp = (const f16x8*)(xh + (size_t)colS[ea] * H);
        f16x8 A[4];
        A[0] = rowp[quad];
        A[1] = rowp[4 + quad];
        A[2] = colp[quad];
        A[3] = colp[4 + quad];

        // ---- attention GEMM ----
        f32x4 ac0 = {0.f, 0.f, 0.f, 0.f}, ac1 = {0.f, 0.f, 0.f, 0.f};
#pragma unroll
        for (int kk = 0; kk < 4; ++kk) {
            ac0 = __builtin_amdgcn_mfma_f32_16x16x32_f16(A[kk], ab[0][kk], ac0, 0, 0, 0);
            ac1 = __builtin_amdgcn_mfma_f32_16x16x32_f16(A[kk], ab[1][kk], ac1, 0, 0, 0);
        }
        // za partials: lane covers feats {l15, 16+l15} for edges quad*4+r
        float p[4];
#pragma unroll
        for (int r = 0; r < 4; ++r) {
            float v0 = fmaxf(ac0[r] + ab1v0, 0.f) * aw20;
            float v1 = fmaxf(ac1[r] + ab1v1, 0.f) * aw21;
            p[r] = v0 + v1;
        }
#pragma unroll
        for (int off = 1; off < 16; off <<= 1) {
#pragma unroll
            for (int r = 0; r < 4; ++r) p[r] += __shfl_xor(p[r], off);
        }
        float fw[4];
#pragma unroll
        for (int r = 0; r < 4; ++r) {
            int eg = ebase + mt * 16 + quad * 4 + r;
            float ewv = (eg < e1) ? ewS[eg] : 0.f;
            fw[r] = ewv / (1.f + __expf(-(p[r] + ab2v)));
        }

        // ---- message GEMM ----
        f32x4 mc[4];
#pragma unroll
        for (int nt = 0; nt < 4; ++nt) {
            f32x4 c = {0.f, 0.f, 0.f, 0.f};
#pragma unroll
            for (int kk = 0; kk < 4; ++kk)
                c = __builtin_amdgcn_mfma_f32_16x16x32_f16(A[kk], mb[nt][kk], c, 0, 0, 0);
            mc[nt] = c;
        }

        // ---- epilogue: h = relu(C + b1) * fw -> hfw (bf16) ----
#pragma unroll
        for (int r = 0; r < 4; ++r) {
            int eg = ebase + mt * 16 + quad * 4 + r;
            if (eg < e1) {
                __hip_bfloat16* dst = hfw + (size_t)(eg - e0) * H + l15;
#pragma unroll
                for (int nt = 0; nt < 4; ++nt)
                    dst[nt * 16] = __float2bfloat16(fmaxf(mc[nt][r] + bm[nt], 0.f) * fw[r]);
            }
        }
        if (l15 < 4) {
            int eg = ebase + mt * 16 + quad * 4 + l15;
            if (eg < e1) fwbuf[eg - e0] = fw[l15];
        }
    }
}

// --------------------------------------------------------------- gather ----
__global__ __launch_bounds__(256) void gather_kernel(
    const __hip_bfloat16* __restrict__ hfw, const float* __restrict__ fwbuf,
    const int* __restrict__ startp, const int* __restrict__ deg,
    float* __restrict__ agg, float* __restrict__ fwsum,
    int N, int e0, int e1)
{
    int wid = (blockIdx.x * 256 + threadIdx.x) >> 6;
    int lane = threadIdx.x & 63;
    if (wid >= N) return;
    int s = startp[wid];
    int endv = s + deg[wid];
    int lo = s > e0 ? s : e0;
    int hi = endv < e1 ? endv : e1;
    if (lo >= hi) return;
    int d = hi - lo;
    int base = lo - e0;
    float acc = 0.f;
    const __hip_bfloat16* hp = hfw + (size_t)base * H + lane;
    for (int i = 0; i < d; ++i) acc += __bfloat162float(hp[(size_t)i * H]);
    float fwl = 0.f;
    for (int i = lane; i < d; i += 64) fwl += fwbuf[base + i];
#pragma unroll
    for (int off = 32; off > 0; off >>= 1) fwl += __shfl_down(fwl, off);
    agg[(size_t)wid * H + lane] += acc;
    if (lane == 0) fwsum[wid] += fwl;
}

// --------------------------------------------------------------- update ----
__global__ __launch_bounds__(256) void update_kernel(
    _Float16* __restrict__ xh, const float* __restrict__ agg,
    const float* __restrict__ fwsum,
    const float* __restrict__ mW2, const float* __restrict__ mb2,
    const float* __restrict__ W1, const float* __restrict__ b1,
    const float* __restrict__ W2, const float* __restrict__ b2, int N)
{
    int n = blockIdx.x * 256 + threadIdx.x;
    if (n >= N) return;
    float fws = fwsum[n];
    float inv = 1.f / fmaxf(fws, 1e-6f);

    union { uint4 v[8]; _Float16 h[64]; } X;
    const uint4* xa = (const uint4*)(xh + (size_t)n * H);
#pragma unroll
    for (int i = 0; i < 8; ++i) X.v[i] = xa[i];
    float xf[H];
#pragma unroll
    for (int j = 0; j < H; ++j) xf[j] = (float)X.h[j];

    float aggv[H];
#pragma unroll
    for (int j = 0; j < H; ++j) aggv[j] = fws * mb2[j];
    const float4* ga = (const float4*)(agg + (size_t)n * H);
    for (int i4 = 0; i4 < H / 4; ++i4) {
        float4 v = ga[i4];
#pragma unroll
        for (int s = 0; s < 4; ++s) {
            float cs = (s == 0) ? v.x : (s == 1) ? v.y : (s == 2) ? v.z : v.w;
            const float* w = mW2 + (i4 * 4 + s) * H;
#pragma unroll
            for (int j = 0; j < H; ++j) aggv[j] += cs * w[j];
        }
    }
#pragma unroll
    for (int j = 0; j < H; ++j) aggv[j] *= inv;

    float accu[H];
#pragma unroll
    for (int j = 0; j < H; ++j) accu[j] = 0.f;
#pragma unroll
    for (int k = 0; k < H; ++k) {
        float cs = xf[k];
        const float* w = W1 + k * H;
#pragma unroll
        for (int j = 0; j < H; ++j) accu[j] += cs * w[j];
    }
#pragma unroll
    for (int k = 0; k < H; ++k) {
        float cs = aggv[k];
        const float* w = W1 + (H + k) * H;
#pragma unroll
        for (int j = 0; j < H; ++j) accu[j] += cs * w[j];
    }

    float h[H];
#pragma unroll
    for (int k = 0; k < H; ++k) h[k] = fmaxf(accu[k] + b1[k], 0.f);
    float acc2[H];
#pragma unroll
    for (int j = 0; j < H; ++j) acc2[j] = b2[j];
#pragma unroll
    for (int k = 0; k < H; ++k) {
        float hk = h[k];
        const float* w = W2 + k * H;
#pragma unroll
        for (int j = 0; j < H; ++j) acc2[j] += hk * w[j];
    }

    union { uint4 v[8]; _Float16 h[64]; } O;
#pragma unroll
    for (int j = 0; j < H; ++j)
        O.h[j] = (_Float16)fmaxf(acc2[j] + xf[j], 0.f);
    uint4* xo = (uint4*)(xh + (size_t)n * H);
#pragma unroll
    for (int i = 0; i < 8; ++i) xo[i] = O.v[i];
}

// ----------------------------------------------------------------- head ----
__global__ __launch_bounds__(256) void max_kernel(
    const _Float16* __restrict__ xh16, unsigned int* __restrict__ serp, int N)
{
    int j = threadIdx.x & (H - 1);
    int g = (blockIdx.x * 256 + threadIdx.x) >> 6;
    int stride = (gridDim.x * 256) >> 6;
    float m = 0.f;  // x >= 0 after relu
    for (int n = g; n < N; n += stride)
        m = fmaxf(m, (float)xh16[(size_t)n * H + j]);
    atomicMax(serp + j, __float_as_uint(m));
}

__global__ void head_kernel(const unsigned int* __restrict__ serp,
                            const float* __restrict__ hW,
                            const float* __restrict__ hb,
                            float* __restrict__ out)
{
    int j = threadIdx.x;  // 64 threads = 1 wave
    float v = __uint_as_float(serp[j]) * hW[j];
#pragma unroll
    for (int off = 32; off > 0; off >>= 1) v += __shfl_down(v, off);
    if (j == 0) out[0] = v + hb[0];
}

// --------------------------------------------------------------- launch ----
extern "C" void kernel_launch(void* const* d_in, const int* in_sizes, int n_in,
                              void* d_out, int out_size, void* d_ws, size_t ws_size,
                              hipStream_t stream)
{
    const float* nf  = (const float*)d_in[0];
    const int*   ei  = (const int*)d_in[1];
    const float* ew  = (const float*)d_in[2];
    const float* eW  = (const float*)d_in[3];
    const float* eb  = (const float*)d_in[4];
    const float* mW1 = (const float*)d_in[5];
    const float* mb1 = (const float*)d_in[6];
    const float* mW2 = (const float*)d_in[7];
    const float* mb2 = (const float*)d_in[8];
    const float* aW1 = (const float*)d_in[9];
    const float* ab1 = (const float*)d_in[10];
    const float* aW2 = (const float*)d_in[11];
    const float* ab2 = (const float*)d_in[12];
    const float* uW1 = (const float*)d_in[13];
    const float* ub1 = (const float*)d_in[14];
    const float* uW2 = (const float*)d_in[15];
    const float* ub2 = (const float*)d_in[16];
    const float* hW  = (const float*)d_in[17];
    const float* hb  = (const float*)d_in[18];

    int N = in_sizes[0] / F;
    int E = in_sizes[2];
    const int* row = ei;
    const int* col = ei + E;

    size_t Nr = ((size_t)N + 3) & ~(size_t)3;
    size_t Er = ((size_t)E + 3) & ~(size_t)3;

    // pick smallest chunk count k whose layout fits ws_size
    int k = 16;
    size_t ce = 0;
    const int kcand[5] = {1, 2, 4, 8, 16};
    for (int i = 0; i < 5; ++i) {
        int kk = kcand[i];
        size_t c = (((size_t)E + kk - 1) / kk + 3) & ~(size_t)3;
        size_t elems = Nr * H / 2     // xh (f16)
                     + Nr * H         // agg
                     + Nr             // fwsum
                     + 64             // serp
                     + 3 * Nr         // deg, startp, cursor
                     + 256            // bsum
                     + 12288          // B-frag buffers (48KB f16)
                     + 3 * Er         // rowS, colS, ewS
                     + c              // fwbuf
                     + c * H / 2;     // hfw (bf16)
        if (elems * 4 <= ws_size || i == 4) { k = kk; ce = c; break; }
    }
    int chunkE = (int)ce;

    _Float16* xh  = (_Float16*)d_ws;                  // Nr*64 f16
    float* agg    = (float*)d_ws + Nr * H / 2;        // Nr*H
    float* fwsum  = agg + Nr * H;                     // Nr
    unsigned int* serp = (unsigned int*)(fwsum + Nr); // 64
    int*   deg    = (int*)(serp + 64);                // Nr
    int*   startp = deg + Nr;                         // Nr
    int*   cursor = startp + Nr;                      // Nr
    int*   bsum   = cursor + Nr;                      // 256
    f16x8* msgB   = (f16x8*)(bsum + 256);             // 2*16*64 = 2048 units
    f16x8* attB   = msgB + 2048;                      // 2*8*64 = 1024 units
    int*   rowS   = (int*)(attB + 1024);              // Er
    int*   colS   = rowS + Er;                        // Er
    float* ewS    = (float*)(colS + Er);              // Er
    float* fwbuf  = ewS + Er;                         // ce
    __hip_bfloat16* hfw = (__hip_bfloat16*)(fwbuf + ce);  // ce*H bf16

    int nb_n = (N + 255) / 256;
    int nb_e = (E + 255) / 256;
    int nb_scan = (N + 1023) / 1024;  // <=256 (N<=262144)

    // ---- counting sort by destination (reused by both layers) ----
    hipMemsetAsync(deg, 0, (size_t)N * sizeof(int), stream);
    hist_kernel<<<nb_e, 256, 0, stream>>>(col, deg, E);
    scan1_kernel<<<nb_scan, 256, 0, stream>>>(deg, startp, bsum, N);
    scan2_kernel<<<1, 256, 0, stream>>>(bsum, nb_scan);
    scan3_kernel<<<nb_n, 256, 0, stream>>>(startp, bsum, cursor, N);
    scatter_kernel<<<nb_e, 256, 0, stream>>>(row, col, ew, cursor,
                                             rowS, colS, ewS, E);

    packfrag_kernel<<<12, 256, 0, stream>>>(mW1, aW1, msgB, attB);
    embed_kernel<<<nb_n, 256, 0, stream>>>(nf, eW, eb, xh, N);

    for (int l = 0; l < 2; ++l) {
        hipMemsetAsync(agg, 0, (Nr * H + Nr) * sizeof(float), stream);
        for (int c = 0; c < k; ++c) {
            int e0 = c * chunkE;
            if (e0 >= E) break;
            int e1 = (e0 + chunkE < E) ? e0 + chunkE : E;
            int nwaves = (e1 - e0 + 63) / 64;
            int nb_c = (nwaves + 3) / 4;
            edge_mfma_kernel<<<nb_c, 256, 0, stream>>>(
                xh, rowS, colS, ewS,
                msgB + (size_t)l * 16 * 64,
                attB + (size_t)l * 8 * 64,
                mb1 + (size_t)l * H,
                ab1 + (size_t)l * (H / 2),
                aW2 + (size_t)l * (H / 2), ab2 + (size_t)l,
                hfw, fwbuf, e0, e1);
            gather_kernel<<<(N + 3) / 4, 256, 0, stream>>>(
                hfw, fwbuf, startp, deg, agg, fwsum, N, e0, e1);
        }
        update_kernel<<<nb_n, 256, 0, stream>>>(
            xh, agg, fwsum,
            mW2 + (size_t)l * H * H,     mb2 + (size_t)l * H,
            uW1 + (size_t)l * 2 * H * H, ub1 + (size_t)l * H,
            uW2 + (size_t)l * H * H,     ub2 + (size_t)l * H, N);
    }

    hipMemsetAsync(serp, 0, 64 * sizeof(unsigned int), stream);
    max_kernel<<<256, 256, 0, stream>>>(xh, serp, N);
    head_kernel<<<1, 64, 0, stream>>>(serp, hW, hb, (float*)d_out);
}

// Round 8
// 840.816 us; speedup vs baseline: 3.4702x; 1.4450x over previous
//
#include <hip/hip_runtime.h>
#include <hip/hip_bf16.h>
#include <math.h>

#define H 64
#define F 18

typedef _Float16 f16x8 __attribute__((ext_vector_type(8)));
typedef float f32x4 __attribute__((ext_vector_type(4)));

// ---------------------------------------------------------------- embed ----
__global__ __launch_bounds__(256) void embed_kernel(
    const float* __restrict__ nf, const float* __restrict__ W,
    const float* __restrict__ b, _Float16* __restrict__ xh, int N)
{
    int n = blockIdx.x * 256 + threadIdx.x;
    if (n >= N) return;
    float acc[H];
#pragma unroll
    for (int j = 0; j < H; ++j) acc[j] = b[j];
    const float* f = nf + (long)n * F;
#pragma unroll
    for (int i = 0; i < F; ++i) {
        float c = f[i];
        const float* w = W + i * H;
#pragma unroll
        for (int j = 0; j < H; ++j) acc[j] += c * w[j];
    }
    union { uint4 v[8]; _Float16 h[64]; } O;
#pragma unroll
    for (int j = 0; j < H; ++j) O.h[j] = (_Float16)fmaxf(acc[j], 0.f);
    uint4* xo = (uint4*)(xh + (size_t)n * H);
#pragma unroll
    for (int i = 0; i < 8; ++i) xo[i] = O.v[i];
}

// ------------------------------------------------- B-fragment prepack -----
// MFMA 16x16x32 B layout: lane holds B[k=kk*32+(lane>>4)*8+j][n=nt*16+(lane&15)]
__global__ __launch_bounds__(256) void packfrag_kernel(
    const float* __restrict__ mW1, const float* __restrict__ aW1,
    f16x8* __restrict__ msgB, f16x8* __restrict__ attB)
{
    int t = blockIdx.x * 256 + threadIdx.x;  // 0..3071
    if (t >= 3072) return;
    int lane = t & 63;
    int frag = t >> 6;            // 0..47
    int l = frag / 24, f = frag % 24;
    int quad = lane >> 4, l15 = lane & 15;
    f16x8 v;
    if (f < 16) {
        int nt = f >> 2, kk = f & 3;
        const float* W = mW1 + (size_t)l * 128 * 64;
#pragma unroll
        for (int j = 0; j < 8; ++j) {
            int k = kk * 32 + quad * 8 + j;
            v[j] = (_Float16)W[k * 64 + nt * 16 + l15];
        }
        msgB[((size_t)l * 16 + f) * 64 + lane] = v;
    } else {
        int f2 = f - 16;
        int nt = f2 >> 2, kk = f2 & 3;
        const float* W = aW1 + (size_t)l * 128 * 32;
#pragma unroll
        for (int j = 0; j < 8; ++j) {
            int k = kk * 32 + quad * 8 + j;
            v[j] = (_Float16)W[k * 32 + nt * 16 + l15];
        }
        attB[((size_t)l * 8 + f2) * 64 + lane] = v;
    }
}

// ---------------------------------------------- update-path precompute ----
// M2U[l] = mW2[l] @ uW1[l][64:128]   (64x64); mbu[l] = mb2[l] @ uW1[l][64:128]
__global__ __launch_bounds__(256) void prep_update_kernel(
    const float* __restrict__ mW2, const float* __restrict__ mb2,
    const float* __restrict__ uW1,
    float* __restrict__ M2U, float* __restrict__ mbu)
{
    int t = blockIdx.x * 256 + threadIdx.x;  // 0..8191
    if (t >= 2 * 64 * 64) return;
    int l = t >> 12, r = t & 4095;
    int i = r >> 6, j = r & 63;
    const float* W2 = mW2 + (size_t)l * 4096;
    const float* U1b = uW1 + (size_t)l * 8192 + 4096;  // rows 64..127
    float s = 0.f;
    for (int k = 0; k < 64; ++k) s += W2[i * 64 + k] * U1b[k * 64 + j];
    M2U[t] = s;
    if (i == 0) {
        float sb = 0.f;
        const float* b2 = mb2 + (size_t)l * 64;
        for (int k = 0; k < 64; ++k) sb += b2[k] * U1b[k * 64 + j];
        mbu[l * 64 + j] = sb;
    }
}

// update B-frags: per layer 24 frags: [0..7]=uW1_top [8..15]=M2U [16..23]=uW2
// frag f -> nt=(f&7)>>1, kk=f&1
__global__ __launch_bounds__(256) void packfrag_upd_kernel(
    const float* __restrict__ uW1, const float* __restrict__ M2U,
    const float* __restrict__ uW2, f16x8* __restrict__ updB)
{
    int t = blockIdx.x * 256 + threadIdx.x;  // 0..3071
    if (t >= 3072) return;
    int lane = t & 63;
    int frag = t >> 6;  // 0..47
    int l = frag / 24, f = frag % 24;
    int quad = lane >> 4, l15 = lane & 15;
    int g = f >> 3, ff = f & 7;
    int nt = ff >> 1, kk = ff & 1;
    const float* src;
    if (g == 0)      src = uW1 + (size_t)l * 8192;       // rows 0..63
    else if (g == 1) src = M2U + (size_t)l * 4096;
    else             src = uW2 + (size_t)l * 4096;
    f16x8 v;
#pragma unroll
    for (int j = 0; j < 8; ++j) {
        int k = kk * 32 + quad * 8 + j;
        v[j] = (_Float16)src[k * 64 + nt * 16 + l15];
    }
    updB[(size_t)frag * 64 + lane] = v;
}

// ----------------------------------------------- counting sort by col -----
__global__ __launch_bounds__(256) void hist_kernel(
    const int* __restrict__ col, int* __restrict__ deg, int E)
{
    int e = blockIdx.x * 256 + threadIdx.x;
    if (e < E) atomicAdd(deg + col[e], 1);
}

__global__ __launch_bounds__(256) void scan1_kernel(
    const int* __restrict__ deg, int* __restrict__ part,
    int* __restrict__ bsum, int N)
{
    __shared__ int lds[256];
    int t = threadIdx.x;
    int base = blockIdx.x * 1024 + t * 4;
    int v[4];
#pragma unroll
    for (int s = 0; s < 4; ++s) v[s] = (base + s < N) ? deg[base + s] : 0;
    int sum = v[0] + v[1] + v[2] + v[3];
    lds[t] = sum;
    __syncthreads();
    for (int off = 1; off < 256; off <<= 1) {
        int xv = (t >= off) ? lds[t - off] : 0;
        __syncthreads();
        lds[t] += xv;
        __syncthreads();
    }
    int excl = lds[t] - sum;
    if (t == 255) bsum[blockIdx.x] = lds[255];
    int p = excl;
#pragma unroll
    for (int s = 0; s < 4; ++s) {
        if (base + s < N) part[base + s] = p;
        p += v[s];
    }
}

__global__ __launch_bounds__(256) void scan2_kernel(int* __restrict__ bsum, int nb)
{
    __shared__ int lds[256];
    int t = threadIdx.x;
    int v = (t < nb) ? bsum[t] : 0;
    lds[t] = v;
    __syncthreads();
    for (int off = 1; off < 256; off <<= 1) {
        int xv = (t >= off) ? lds[t - off] : 0;
        __syncthreads();
        lds[t] += xv;
        __syncthreads();
    }
    if (t < nb) bsum[t] = lds[t] - v;
}

__global__ __launch_bounds__(256) void scan3_kernel(
    int* __restrict__ part, const int* __restrict__ bsum,
    int* __restrict__ cursor, int N)
{
    int i = blockIdx.x * 256 + threadIdx.x;
    if (i >= N) return;
    int s = part[i] + bsum[i >> 10];
    part[i] = s;
    cursor[i] = s;
}

__global__ __launch_bounds__(256) void scatter_kernel(
    const int* __restrict__ row, const int* __restrict__ col,
    const float* __restrict__ ew, int* __restrict__ cursor,
    int* __restrict__ rowS, int* __restrict__ colS,
    float* __restrict__ ewS, int E)
{
    int e = blockIdx.x * 256 + threadIdx.x;
    if (e >= E) return;
    int c = col[e];
    int p = atomicAdd(cursor + c, 1);
    rowS[p] = row[e];
    colS[p] = c;
    ewS[p] = ew[e];
}

// ----------------------------------------------------------------- edge ----
__global__ __launch_bounds__(256) void edge_mfma_kernel(
    const _Float16* __restrict__ xh,
    const int* __restrict__ rowS, const int* __restrict__ colS,
    const float* __restrict__ ewS,
    const f16x8* __restrict__ msgB,  // [16][64] for this layer
    const f16x8* __restrict__ attB,  // [8][64]
    const float* __restrict__ b1, const float* __restrict__ ab1,
    const float* __restrict__ aW2, const float* __restrict__ ab2,
    __hip_bfloat16* __restrict__ hfw, float* __restrict__ fwbuf,
    int e0, int e1)
{
    int wid = (blockIdx.x * 256 + threadIdx.x) >> 6;
    int lane = threadIdx.x & 63;
    int ebase = e0 + wid * 64;
    if (ebase >= e1) return;
    int quad = lane >> 4, l15 = lane & 15;

    f16x8 mb[4][4], ab[2][4];
#pragma unroll
    for (int nt = 0; nt < 4; ++nt)
#pragma unroll
        for (int kk = 0; kk < 4; ++kk)
            mb[nt][kk] = msgB[(nt * 4 + kk) * 64 + lane];
#pragma unroll
    for (int nt = 0; nt < 2; ++nt)
#pragma unroll
        for (int kk = 0; kk < 4; ++kk)
            ab[nt][kk] = attB[(nt * 4 + kk) * 64 + lane];

    float ab1v0 = ab1[l15], ab1v1 = ab1[16 + l15];
    float aw20 = aW2[l15], aw21 = aW2[16 + l15];
    float ab2v = ab2[0];
    float bm[4];
#pragma unroll
    for (int nt = 0; nt < 4; ++nt) bm[nt] = b1[nt * 16 + l15];

    for (int mt = 0; mt < 4; ++mt) {
        int ea = ebase + mt * 16 + l15;
        if (ea >= e1) ea = e1 - 1;
        const f16x8* rowp = (const f16x8*)(xh + (size_t)rowS[ea] * H);
        const f16x8* colp = (const f16x8*)(xh + (size_t)colS[ea] * H);
        f16x8 A[4];
        A[0] = rowp[quad];
        A[1] = rowp[4 + quad];
        A[2] = colp[quad];
        A[3] = colp[4 + quad];

        f32x4 ac0 = {0.f, 0.f, 0.f, 0.f}, ac1 = {0.f, 0.f, 0.f, 0.f};
#pragma unroll
        for (int kk = 0; kk < 4; ++kk) {
            ac0 = __builtin_amdgcn_mfma_f32_16x16x32_f16(A[kk], ab[0][kk], ac0, 0, 0, 0);
            ac1 = __builtin_amdgcn_mfma_f32_16x16x32_f16(A[kk], ab[1][kk], ac1, 0, 0, 0);
        }
        float p[4];
#pragma unroll
        for (int r = 0; r < 4; ++r) {
            float v0 = fmaxf(ac0[r] + ab1v0, 0.f) * aw20;
            float v1 = fmaxf(ac1[r] + ab1v1, 0.f) * aw21;
            p[r] = v0 + v1;
        }
#pragma unroll
        for (int off = 1; off < 16; off <<= 1) {
#pragma unroll
            for (int r = 0; r < 4; ++r) p[r] += __shfl_xor(p[r], off);
        }
        float fw[4];
#pragma unroll
        for (int r = 0; r < 4; ++r) {
            int eg = ebase + mt * 16 + quad * 4 + r;
            float ewv = (eg < e1) ? ewS[eg] : 0.f;
            fw[r] = ewv / (1.f + __expf(-(p[r] + ab2v)));
        }

        f32x4 mc[4];
#pragma unroll
        for (int nt = 0; nt < 4; ++nt) {
            f32x4 c = {0.f, 0.f, 0.f, 0.f};
#pragma unroll
            for (int kk = 0; kk < 4; ++kk)
                c = __builtin_amdgcn_mfma_f32_16x16x32_f16(A[kk], mb[nt][kk], c, 0, 0, 0);
            mc[nt] = c;
        }

#pragma unroll
        for (int r = 0; r < 4; ++r) {
            int eg = ebase + mt * 16 + quad * 4 + r;
            if (eg < e1) {
                __hip_bfloat16* dst = hfw + (size_t)(eg - e0) * H + l15;
#pragma unroll
                for (int nt = 0; nt < 4; ++nt)
                    dst[nt * 16] = __float2bfloat16(fmaxf(mc[nt][r] + bm[nt], 0.f) * fw[r]);
            }
        }
        if (l15 < 4) {
            int eg = ebase + mt * 16 + quad * 4 + l15;
            if (eg < e1) fwbuf[eg - e0] = fw[l15];
        }
    }
}

// --------------------------------------------------------------- gather ----
__global__ __launch_bounds__(256) void gather_kernel(
    const __hip_bfloat16* __restrict__ hfw, const float* __restrict__ fwbuf,
    const int* __restrict__ startp, const int* __restrict__ deg,
    float* __restrict__ agg, float* __restrict__ fwsum,
    int N, int e0, int e1)
{
    int wid = (blockIdx.x * 256 + threadIdx.x) >> 6;
    int lane = threadIdx.x & 63;
    if (wid >= N) return;
    int s = startp[wid];
    int endv = s + deg[wid];
    int lo = s > e0 ? s : e0;
    int hi = endv < e1 ? endv : e1;
    if (lo >= hi) return;
    int d = hi - lo;
    int base = lo - e0;
    float acc = 0.f;
    const __hip_bfloat16* hp = hfw + (size_t)base * H + lane;
    for (int i = 0; i < d; ++i) acc += __bfloat162float(hp[(size_t)i * H]);
    float fwl = 0.f;
    for (int i = lane; i < d; i += 64) fwl += fwbuf[base + i];
#pragma unroll
    for (int off = 32; off > 0; off >>= 1) fwl += __shfl_down(fwl, off);
    agg[(size_t)wid * H + lane] += acc;
    if (lane == 0) fwsum[wid] += fwl;
}

// --------------------------------------------------------------- update ----
// MFMA: wave = 64 nodes (4 M-tiles). Algebraic fold:
//   accu = x@uW1_top + inv*(agg@M2U) + (fws*inv)*mbu ; h=relu(accu+ub1)
//   out  = relu(h@uW2 + ub2 + x)
// One LDS transpose (C-layout h -> A-layout), wave-private buffer.
__global__ __launch_bounds__(256, 2) void update_mfma_kernel(
    _Float16* __restrict__ xh, const float* __restrict__ agg,
    const float* __restrict__ fwsum,
    const f16x8* __restrict__ Bfrag,  // [24][64] this layer
    const float* __restrict__ mbu,    // [64]
    const float* __restrict__ ub1, const float* __restrict__ ub2, int N)
{
    __shared__ __align__(16) _Float16 hlds[4][16 * 80];  // pad 80 -> 16B rows
    int wib = threadIdx.x >> 6;
    int lane = threadIdx.x & 63;
    int wid = (blockIdx.x * 256 + threadIdx.x) >> 6;
    int quad = lane >> 4, l15 = lane & 15;
    int nbase = wid * 64;
    if (nbase >= N) return;

    f16x8 Bu[8], Bm[8], Bw[8];
#pragma unroll
    for (int i = 0; i < 8; ++i) {
        Bu[i] = Bfrag[i * 64 + lane];
        Bm[i] = Bfrag[(8 + i) * 64 + lane];
        Bw[i] = Bfrag[(16 + i) * 64 + lane];
    }
    float mbuv[4], b1v[4], b2v[4];
#pragma unroll
    for (int nt = 0; nt < 4; ++nt) {
        mbuv[nt] = mbu[nt * 16 + l15];
        b1v[nt] = ub1[nt * 16 + l15];
        b2v[nt] = ub2[nt * 16 + l15];
    }

    for (int mt = 0; mt < 4; ++mt) {
        int na = nbase + mt * 16 + l15;
        if (na >= N) na = N - 1;
        const f16x8* xrow = (const f16x8*)(xh + (size_t)na * H);
        f16x8 Ax[2];
        Ax[0] = xrow[quad];
        Ax[1] = xrow[4 + quad];
        const float4* arow = (const float4*)(agg + (size_t)na * H);
        f16x8 Aa[2];
#pragma unroll
        for (int kk = 0; kk < 2; ++kk) {
            float4 a0 = arow[kk * 8 + quad * 2];
            float4 a1 = arow[kk * 8 + quad * 2 + 1];
            f16x8 v;
            v[0] = (_Float16)a0.x; v[1] = (_Float16)a0.y;
            v[2] = (_Float16)a0.z; v[3] = (_Float16)a0.w;
            v[4] = (_Float16)a1.x; v[5] = (_Float16)a1.y;
            v[6] = (_Float16)a1.z; v[7] = (_Float16)a1.w;
            Aa[kk] = v;
        }

        f32x4 Cx[4], Ca[4];
#pragma unroll
        for (int nt = 0; nt < 4; ++nt) {
            f32x4 cx = {0.f, 0.f, 0.f, 0.f}, ca = {0.f, 0.f, 0.f, 0.f};
#pragma unroll
            for (int kk = 0; kk < 2; ++kk) {
                cx = __builtin_amdgcn_mfma_f32_16x16x32_f16(Ax[kk], Bu[nt * 2 + kk], cx, 0, 0, 0);
                ca = __builtin_amdgcn_mfma_f32_16x16x32_f16(Aa[kk], Bm[nt * 2 + kk], ca, 0, 0, 0);
            }
            Cx[nt] = cx; Ca[nt] = ca;
        }

        int noder = nbase + mt * 16 + quad * 4;  // C-layout rows
        float fws_r[4], inv_r[4];
#pragma unroll
        for (int r = 0; r < 4; ++r) {
            int ng = noder + r; if (ng >= N) ng = N - 1;
            float fws = fwsum[ng];
            fws_r[r] = fws;
            inv_r[r] = 1.f / fmaxf(fws, 1e-6f);
        }

        // h (C-layout) -> LDS (A-layout rows)
#pragma unroll
        for (int nt = 0; nt < 4; ++nt) {
#pragma unroll
            for (int r = 0; r < 4; ++r) {
                float hv = fmaxf(Cx[nt][r] + inv_r[r] * Ca[nt][r]
                                 + fws_r[r] * inv_r[r] * mbuv[nt] + b1v[nt], 0.f);
                hlds[wib][(quad * 4 + r) * 80 + nt * 16 + l15] = (_Float16)hv;
            }
        }
        __asm__ __volatile__("s_waitcnt lgkmcnt(0)" ::: "memory");
        f16x8 Ah[2];
        Ah[0] = *(const f16x8*)&hlds[wib][l15 * 80 + quad * 8];
        Ah[1] = *(const f16x8*)&hlds[wib][l15 * 80 + 32 + quad * 8];
        __asm__ __volatile__("s_waitcnt lgkmcnt(0)" ::: "memory");

        f32x4 C2[4];
#pragma unroll
        for (int nt = 0; nt < 4; ++nt) {
            f32x4 c = {0.f, 0.f, 0.f, 0.f};
#pragma unroll
            for (int kk = 0; kk < 2; ++kk)
                c = __builtin_amdgcn_mfma_f32_16x16x32_f16(Ah[kk], Bw[nt * 2 + kk], c, 0, 0, 0);
            C2[nt] = c;
        }

        // epilogue: out = relu(C2 + ub2 + x_old), C-layout element-wise
#pragma unroll
        for (int r = 0; r < 4; ++r) {
            int ng = noder + r;
            if (ng < N) {
#pragma unroll
                for (int nt = 0; nt < 4; ++nt) {
                    size_t idx = (size_t)ng * H + nt * 16 + l15;
                    float xo = (float)xh[idx];
                    xh[idx] = (_Float16)fmaxf(C2[nt][r] + b2v[nt] + xo, 0.f);
                }
            }
        }
    }
}

// ----------------------------------------------------------------- head ----
__global__ __launch_bounds__(256) void max_kernel(
    const _Float16* __restrict__ xh16, unsigned int* __restrict__ serp, int N)
{
    int j = threadIdx.x & (H - 1);
    int g = (blockIdx.x * 256 + threadIdx.x) >> 6;
    int stride = (gridDim.x * 256) >> 6;
    float m = 0.f;  // x >= 0 after relu
    for (int n = g; n < N; n += stride)
        m = fmaxf(m, (float)xh16[(size_t)n * H + j]);
    atomicMax(serp + j, __float_as_uint(m));
}

__global__ void head_kernel(const unsigned int* __restrict__ serp,
                            const float* __restrict__ hW,
                            const float* __restrict__ hb,
                            float* __restrict__ out)
{
    int j = threadIdx.x;  // 64 threads = 1 wave
    float v = __uint_as_float(serp[j]) * hW[j];
#pragma unroll
    for (int off = 32; off > 0; off >>= 1) v += __shfl_down(v, off);
    if (j == 0) out[0] = v + hb[0];
}

// --------------------------------------------------------------- launch ----
extern "C" void kernel_launch(void* const* d_in, const int* in_sizes, int n_in,
                              void* d_out, int out_size, void* d_ws, size_t ws_size,
                              hipStream_t stream)
{
    const float* nf  = (const float*)d_in[0];
    const int*   ei  = (const int*)d_in[1];
    const float* ew  = (const float*)d_in[2];
    const float* eW  = (const float*)d_in[3];
    const float* eb  = (const float*)d_in[4];
    const float* mW1 = (const float*)d_in[5];
    const float* mb1 = (const float*)d_in[6];
    const float* mW2 = (const float*)d_in[7];
    const float* mb2 = (const float*)d_in[8];
    const float* aW1 = (const float*)d_in[9];
    const float* ab1 = (const float*)d_in[10];
    const float* aW2 = (const float*)d_in[11];
    const float* ab2 = (const float*)d_in[12];
    const float* uW1 = (const float*)d_in[13];
    const float* ub1 = (const float*)d_in[14];
    const float* uW2 = (const float*)d_in[15];
    const float* ub2 = (const float*)d_in[16];
    const float* hW  = (const float*)d_in[17];
    const float* hb  = (const float*)d_in[18];

    int N = in_sizes[0] / F;
    int E = in_sizes[2];
    const int* row = ei;
    const int* col = ei + E;

    size_t Nr = ((size_t)N + 3) & ~(size_t)3;
    size_t Er = ((size_t)E + 3) & ~(size_t)3;

    // pick smallest chunk count k whose layout fits ws_size
    int k = 16;
    size_t ce = 0;
    const int kcand[5] = {1, 2, 4, 8, 16};
    for (int i = 0; i < 5; ++i) {
        int kk = kcand[i];
        size_t c = (((size_t)E + kk - 1) / kk + 3) & ~(size_t)3;
        size_t elems = Nr * H / 2     // xh (f16)
                     + Nr * H         // agg
                     + Nr             // fwsum
                     + 64             // serp
                     + 3 * Nr         // deg, startp, cursor
                     + 256            // bsum
                     + 12288          // msgB+attB (48KB f16)
                     + 8192 + 128     // M2U, mbu
                     + 12288          // updB (48KB f16)
                     + 3 * Er         // rowS, colS, ewS
                     + c              // fwbuf
                     + c * H / 2;     // hfw (bf16)
        if (elems * 4 <= ws_size || i == 4) { k = kk; ce = c; break; }
    }
    int chunkE = (int)ce;

    _Float16* xh  = (_Float16*)d_ws;                  // Nr*64 f16
    float* agg    = (float*)d_ws + Nr * H / 2;        // Nr*H
    float* fwsum  = agg + Nr * H;                     // Nr
    unsigned int* serp = (unsigned int*)(fwsum + Nr); // 64
    int*   deg    = (int*)(serp + 64);                // Nr
    int*   startp = deg + Nr;                         // Nr
    int*   cursor = startp + Nr;                      // Nr
    int*   bsum   = cursor + Nr;                      // 256
    f16x8* msgB   = (f16x8*)(bsum + 256);             // 2048 units
    f16x8* attB   = msgB + 2048;                      // 1024 units
    float* M2U    = (float*)(attB + 1024);            // 8192
    float* mbu    = M2U + 8192;                       // 128
    f16x8* updB   = (f16x8*)(mbu + 128);              // 3072 units
    int*   rowS   = (int*)(updB + 3072);              // Er
    int*   colS   = rowS + Er;                        // Er
    float* ewS    = (float*)(colS + Er);              // Er
    float* fwbuf  = ewS + Er;                         // ce
    __hip_bfloat16* hfw = (__hip_bfloat16*)(fwbuf + ce);  // ce*H bf16

    int nb_n = (N + 255) / 256;
    int nb_e = (E + 255) / 256;
    int nb_scan = (N + 1023) / 1024;  // <=256 (N<=262144)

    // ---- counting sort by destination (reused by both layers) ----
    hipMemsetAsync(deg, 0, (size_t)N * sizeof(int), stream);
    hist_kernel<<<nb_e, 256, 0, stream>>>(col, deg, E);
    scan1_kernel<<<nb_scan, 256, 0, stream>>>(deg, startp, bsum, N);
    scan2_kernel<<<1, 256, 0, stream>>>(bsum, nb_scan);
    scan3_kernel<<<nb_n, 256, 0, stream>>>(startp, bsum, cursor, N);
    scatter_kernel<<<nb_e, 256, 0, stream>>>(row, col, ew, cursor,
                                             rowS, colS, ewS, E);

    packfrag_kernel<<<12, 256, 0, stream>>>(mW1, aW1, msgB, attB);
    prep_update_kernel<<<32, 256, 0, stream>>>(mW2, mb2, uW1, M2U, mbu);
    packfrag_upd_kernel<<<12, 256, 0, stream>>>(uW1, M2U, uW2, updB);
    embed_kernel<<<nb_n, 256, 0, stream>>>(nf, eW, eb, xh, N);

    for (int l = 0; l < 2; ++l) {
        hipMemsetAsync(agg, 0, (Nr * H + Nr) * sizeof(float), stream);
        for (int c = 0; c < k; ++c) {
            int e0 = c * chunkE;
            if (e0 >= E) break;
            int e1 = (e0 + chunkE < E) ? e0 + chunkE : E;
            int nwaves = (e1 - e0 + 63) / 64;
            int nb_c = (nwaves + 3) / 4;
            edge_mfma_kernel<<<nb_c, 256, 0, stream>>>(
                xh, rowS, colS, ewS,
                msgB + (size_t)l * 16 * 64,
                attB + (size_t)l * 8 * 64,
                mb1 + (size_t)l * H,
                ab1 + (size_t)l * (H / 2),
                aW2 + (size_t)l * (H / 2), ab2 + (size_t)l,
                hfw, fwbuf, e0, e1);
            gather_kernel<<<(N + 3) / 4, 256, 0, stream>>>(
                hfw, fwbuf, startp, deg, agg, fwsum, N, e0, e1);
        }
        int nwaves_n = (N + 63) / 64;
        update_mfma_kernel<<<(nwaves_n + 3) / 4, 256, 0, stream>>>(
            xh, agg, fwsum,
            updB + (size_t)l * 24 * 64,
            mbu + (size_t)l * 64,
            ub1 + (size_t)l * H, ub2 + (size_t)l * H, N);
    }

    hipMemsetAsync(serp, 0, 64 * sizeof(unsigned int), stream);
    max_kernel<<<256, 256, 0, stream>>>(xh, serp, N);
    head_kernel<<<1, 64, 0, stream>>>(serp, hW, hb, (float*)d_out);
}